// Round 14
// baseline (289.097 us; speedup 1.0000x reference)
//
#include <hip/hip_runtime.h>

typedef _Float16 f16;
typedef f16 f16x4 __attribute__((ext_vector_type(4)));
typedef f16 f16x8 __attribute__((ext_vector_type(8)));
typedef float f32x2 __attribute__((ext_vector_type(2)));
typedef float f32x4 __attribute__((ext_vector_type(4)));
typedef float f32x16 __attribute__((ext_vector_type(16)));
typedef unsigned int uint32;

#define FIN  64
#define FOUT 64
#define HI   128
#define WI   128
#define HO   126
#define WO   126
#define HIWI (HI*WI)
#define NPH  8       // phases, 8 input channels each (8 barriers total)
#define CPH  8
#define TR   8       // tile rows
#define TC   16      // tile cols
#define SR   10      // staged rows (TR+2)
#define SDW  12      // dwords per staged row (10 used, 2 pad)
#define CHSTR (SR*SDW)        // 120 dwords per channel block
#define ONES_OFF (CPH*CHSTR)  // 960: shared 1.0h row (bias slot)
#define XBUF (ONES_OFF+SDW)   // 972 dwords per buffer
#define NUNIT 400             // float4 staging units per phase (8ch x 50)

// ws: weight B-fragment table f16 [i][ob][lane][8] = 128 KiB.
// k-labeling (validated rounds 6/8/9/10): k = g*4+(j&3)+8*(j>>2), g=lane>>5;
// taps k=4*dy+dx (dx<3 real, dx=3 zero-weight), k12 = bias (pixel side = 1.0h).
// LESSONS: (r11) never take the address of an MFMA result vector -> scratch.
// (r12) never pass register arrays by reference -> SROA fails -> scratch.
// Packed f32x2 built via element CONSTRUCTORS ({S[0],S[1]}) is SSA-safe.

__global__ __launch_bounds__(256) void prepass(
    const float* __restrict__ Wf, const float* __restrict__ bf,
    unsigned short* __restrict__ ws)
{
    int t = blockIdx.x * 256 + threadIdx.x;   // 0..8191
    int i  = t >> 7;
    int ob = (t >> 6) & 1;
    int l  = t & 63;
    int g  = l >> 5, n = l & 31;
    int o  = ob * 32 + n;
    unsigned short h[8];
#pragma unroll
    for (int j = 0; j < 8; ++j) {
        int k = g * 4 + (j & 3) + 8 * (j >> 2);
        float v = 0.0f;
        if (k < 12) {
            int dy = k >> 2, dx = k & 3;
            if (dx < 3) v = Wf[((size_t)o * FIN + i) * 9 + dy * 3 + dx];
        } else if (k == 12) {
            v = bf[o * FIN + i];
        }
        f16 hv = (f16)v;
        h[j] = *(unsigned short*)&hv;
    }
    uint4 pk;
    pk.x = h[0] | ((uint32)h[1] << 16);
    pk.y = h[2] | ((uint32)h[3] << 16);
    pk.z = h[4] | ((uint32)h[5] << 16);
    pk.w = h[6] | ((uint32)h[7] << 16);
    *(uint4*)&ws[(size_t)t * 8] = pk;
}

__global__ __launch_bounds__(256, 4) void conv_mfma(
    const float* __restrict__ x,  const float* __restrict__ Wc,
    const float* __restrict__ bc, const unsigned short* __restrict__ ws,
    float* __restrict__ out)
{
    __shared__ __align__(16) union {
        struct { uint32 xsl[2][XBUF]; float wcl[32][68]; } a;  // 16.5 KB
        float ot[32][132];                                     // 16.9 KB
    } sm;

    const int tid = threadIdx.x;
    const int l   = tid & 63, w = tid >> 6;
    const int g   = l >> 5;
    const int m   = l & 31;          // A-row (pixel) on loads; C-col (o) on output
    const int prow = m >> 2;
    // wave-uniform column parity: even waves own even cols, odd waves odd cols
    const int qd   = (w & 1) * 4 + (m & 3);   // first dword of the window
    const int shl  = (w >> 1) * 16;           // alignbit shift: 0 or 16 (uniform)

    // XCD-group swizzle: all 16 blocks sharing (rx,b) -> same fid%8 (same XCD)
    const int fid    = blockIdx.x;
    const int grp    = (fid >> 7) * 8 + (fid & 7);   // 0..63 = rx + 16*b
    const int member = (fid >> 3) & 15;              // cy + 8*oh
    const int rx = grp & 15, b = grp >> 4;
    const int cy = member & 7, oh = member >> 3;
    const int row0 = rx * TR;
    const int col0 = cy * TC;
    const int o_lane = oh * 32 + m;

    // ---- stage Wc [oo][i] (coalesced: Wc input is already [o][i]) ----
#pragma unroll
    for (int k = 0; k < 8; ++k) {
        int idx = tid + k * 256;                      // 0..2047
        sm.a.wcl[idx >> 6][idx & 63] =
            Wc[(size_t)(oh * 32 + (idx >> 6)) * FIN + (idx & 63)];
    }
    // ones rows (bias slot source), both buffers
    if (tid < 2 * SDW) sm.a.xsl[tid / SDW][ONES_OFF + tid % SDW] = 0x3c003c00u;

    // ---- staging map: 400 units, one aligned float4 each; <=2 per thread ----
    const float* xb = x + (size_t)b * FIN * HIWI;
    const bool uv1 = (tid < NUNIT - 256);
    int uch0, goff0, widx0, uch1 = 0, goff1 = 0, widx1 = 0;
    {
        int unit = tid;
        uch0 = unit / 50;
        int rem = unit % 50;
        int r = rem / 5, u = rem % 5;
        int gy = min(row0 + r, HI - 1);
        int gx = min(col0 + 4 * u, WI - 4);
        goff0 = gy * WI + gx;
        widx0 = uch0 * CHSTR + r * SDW + 2 * u;
    }
    if (uv1) {
        int unit = tid + 256;
        uch1 = unit / 50;
        int rem = unit % 50;
        int r = rem / 5, u = rem % 5;
        int gy = min(row0 + r, HI - 1);
        int gx = min(col0 + 4 * u, WI - 4);
        goff1 = gy * WI + gx;
        widx1 = uch1 * CHSTR + r * SDW + 2 * u;
    }

    // prologue: stage channels 0..7 into buffer 0
    {
        f32x4 v = *(const f32x4*)&xb[(size_t)uch0 * HIWI + goff0];
        f16x4 h; h[0] = (f16)v[0]; h[1] = (f16)v[1]; h[2] = (f16)v[2]; h[3] = (f16)v[3];
        *(uint2*)&sm.a.xsl[0][widx0] = *(uint2*)&h;
        if (uv1) {
            f32x4 v1 = *(const f32x4*)&xb[(size_t)uch1 * HIWI + goff1];
            f16x4 h1; h1[0] = (f16)v1[0]; h1[1] = (f16)v1[1];
            h1[2] = (f16)v1[2]; h1[3] = (f16)v1[3];
            *(uint2*)&sm.a.xsl[0][widx1] = *(uint2*)&h1;
        }
    }

    // B-fragment quad prefetch (channels 0..3)
    const uint4* Btab = (const uint4*)ws;
    uint4 Bq[4], Bn[4];
#pragma unroll
    for (int q = 0; q < 4; ++q)
        Bq[q] = Btab[(size_t)(q * 2 + oh) * 64 + l];

    f32x2 acc2[8];
#pragma unroll
    for (int j = 0; j < 8; ++j) acc2[j] = (f32x2){0.0f, 0.0f};
    const f32x16 zero = {};
    const f32x2  z2   = {0.0f, 0.0f};

    // hoisted read offsets (per-thread constants)
    const int r1off = (prow + g) * SDW + qd;
    const int r2off = g ? (ONES_OFF + qd) : ((prow + 2) * SDW + qd);
    const int r2str = g ? 0 : CHSTR;

    for (int ph = 0; ph < NPH; ++ph) {         // plain loop: arrays stay in VGPRs
        const int cur = ph & 1;
        const bool more = (ph + 1 < NPH);

        f32x4 sv0 = {}, sv1 = {};
        if (more) {
            const int ib = (ph + 1) * CPH;
            sv0 = *(const f32x4*)&xb[(size_t)(ib + uch0) * HIWI + goff0];
            if (uv1) sv1 = *(const f32x4*)&xb[(size_t)(ib + uch1) * HIWI + goff1];
        }

        __syncthreads();   // buf[cur] writes from previous phase visible

        const f32x4 wcqA = *(const f32x4*)&sm.a.wcl[m][ph * CPH];
        const f32x4 wcqB = *(const f32x4*)&sm.a.wcl[m][ph * CPH + 4];
        const uint32* base = sm.a.xsl[cur];

#pragma unroll
        for (int half = 0; half < 2; ++half) {
            // issue next-quad B loads (consumed after this quad's compute)
            const int cn = min(ph * CPH + half * 4 + 4, FIN - 4);
#pragma unroll
            for (int q = 0; q < 4; ++q)
                Bn[q] = Btab[(size_t)((cn + q) * 2 + oh) * 64 + l];

#pragma unroll
            for (int c4 = 0; c4 < 4; ++c4) {
                const int ch = half * 4 + c4;
                const uint32* r1 = base + ch * CHSTR + r1off;
                const uint32* r2 = base + ch * r2str + r2off;
                uint32 d0 = r1[0], d1 = r1[1], d2 = r1[2];
                uint32 e0 = r2[0], e1 = r2[1], e2 = r2[2];
                uint32 a0 = __builtin_amdgcn_alignbit(d1, d0, shl);
                uint32 a1 = __builtin_amdgcn_alignbit(d2, d1, shl);
                uint32 b0 = __builtin_amdgcn_alignbit(e1, e0, shl);
                uint32 b1 = __builtin_amdgcn_alignbit(e2, e1, shl);
                uint4 auv = {a0, a1, b0, b1};
                f16x8 Af = *(f16x8*)&auv;
                f16x8 Bf = *(f16x8*)&Bq[c4];
                f32x16 S = __builtin_amdgcn_mfma_f32_32x32x16_f16(Af, Bf, zero, 0, 0, 0);
                const float wcv = half ? wcqB[c4] : wcqA[c4];
                const f32x2 wc2 = {wcv, wcv};
#pragma unroll
                for (int j = 0; j < 8; ++j) {
                    f32x2 s2 = {S[2 * j], S[2 * j + 1]};   // SSA pack, no alloca
                    f32x2 mx = __builtin_elementwise_max(s2, z2);
                    acc2[j] = __builtin_elementwise_fma(wc2, mx, acc2[j]);
                }
            }
#pragma unroll
            for (int q = 0; q < 4; ++q) Bq[q] = Bn[q];
        }

        if (more) {
            f16x4 h; h[0] = (f16)sv0[0]; h[1] = (f16)sv0[1];
            h[2] = (f16)sv0[2]; h[3] = (f16)sv0[3];
            *(uint2*)&sm.a.xsl[cur ^ 1][widx0] = *(uint2*)&h;
            if (uv1) {
                f16x4 h1; h1[0] = (f16)sv1[0]; h1[1] = (f16)sv1[1];
                h1[2] = (f16)sv1[2]; h1[3] = (f16)sv1[3];
                *(uint2*)&sm.a.xsl[cur ^ 1][widx1] = *(uint2*)&h1;
            }
        }
    }

    __syncthreads();   // xsl/wcl dead -> reuse LDS as transpose buffer

    // ---- transpose: ot[o][px], px row-major in the 8x16 tile ----
    const float bcv = bc[o_lane];
#pragma unroll
    for (int r = 0; r < 16; ++r) {
        int p  = (r & 3) + 8 * (r >> 2) + 4 * g;                 // wave-local pixel
        int px = (p >> 2) * TC + (w & 1) * 8 + 2 * (p & 3) + (w >> 1);
        sm.ot[m][px] = acc2[r >> 1][r & 1] + bcv;
    }
    __syncthreads();

    // ---- stores: one 16-col row chunk (64B) per thread ----
    {
        const int oo  = tid >> 3;          // 0..31
        const int seg = tid & 7;           // tile row
        const int o   = oh * 32 + oo;
        const int ho  = row0 + seg;
        if (ho < HO) {
            const float* src = &sm.ot[oo][seg * TC];
            size_t base = ((size_t)(b * FOUT + o) * HO + ho) * WO + col0;
            const int nst = (col0 + TC <= WO) ? TC : (WO - col0);
            for (int c = 0; c < nst; ++c) out[base + c] = src[c];
        }
    }
}

extern "C" void kernel_launch(void* const* d_in, const int* in_sizes, int n_in,
                              void* d_out, int out_size, void* d_ws, size_t ws_size,
                              hipStream_t stream) {
    const float* x  = (const float*)d_in[0];
    const float* Wf = (const float*)d_in[1];
    const float* bf = (const float*)d_in[2];
    const float* Wc = (const float*)d_in[3];
    const float* bc = (const float*)d_in[4];
    float* out = (float*)d_out;
    unsigned short* ws = (unsigned short*)d_ws;

    hipLaunchKernelGGL(prepass, dim3(32), dim3(256), 0, stream, Wf, bf, ws);

    // 1024 blocks: 16 rx x (8 cy x 2 oh) x 4 b, XCD-group swizzled
    hipLaunchKernelGGL(conv_mfma, dim3(1024), dim3(256), 0, stream,
                       x, Wc, bc, ws, out);
}

// Round 15
// 46.741 us; speedup vs baseline: 6.1851x; 6.1851x over previous
//
#include <hip/hip_runtime.h>

typedef _Float16 f16;
typedef f16 f16x4 __attribute__((ext_vector_type(4)));
typedef f16 f16x8 __attribute__((ext_vector_type(8)));
typedef float f32x4 __attribute__((ext_vector_type(4)));
typedef float f32x16 __attribute__((ext_vector_type(16)));
typedef unsigned int uint32;

#define FIN  64
#define FOUT 64
#define HI   128
#define WI   128
#define HO   126
#define WO   126
#define HIWI (HI*WI)
#define NPH  8       // phases; each stages 8 channels (4 per wave-group)
#define TR   8       // tile rows
#define TC   16      // tile cols
#define SR   10      // staged rows (TR+2)
#define SDW  12      // dwords per staged row (10 used, 2 pad)
#define CHSTR (SR*SDW)     // 120 dwords per channel slot
#define NSLOT 8            // channel slots per phase (2 groups x 4)
#define XBUF (NSLOT*CHSTR) // 960 dwords per buffer
#define NUNIT 400          // float4 staging units per phase (8ch x 50)

// ws: weight B-fragment table f16 [i][ob][lane][8] = 128 KiB.
// k-labeling (validated rounds 6/8/9/10): k = g*4+(j&3)+8*(j>>2), g=lane>>5;
// taps k=4*dy+dx (dx<3 real, dx=3 zero-weight), k12 = bias (pixel side = 1.0h).
// LESSONS: (r11) no address-of MFMA results; (r12) no register arrays by
// reference; (r14) don't exceed the VGPR budget with bundled state (spill ->
// GBs of scratch). This round: round-10 inner loop VERBATIM; one change =
// 8-wave channel-split block with LDS partial-sum combine.

__global__ __launch_bounds__(256) void prepass(
    const float* __restrict__ Wf, const float* __restrict__ bf,
    unsigned short* __restrict__ ws)
{
    int t = blockIdx.x * 256 + threadIdx.x;   // 0..8191
    int i  = t >> 7;
    int ob = (t >> 6) & 1;
    int l  = t & 63;
    int g  = l >> 5, n = l & 31;
    int o  = ob * 32 + n;
    unsigned short h[8];
#pragma unroll
    for (int j = 0; j < 8; ++j) {
        int k = g * 4 + (j & 3) + 8 * (j >> 2);
        float v = 0.0f;
        if (k < 12) {
            int dy = k >> 2, dx = k & 3;
            if (dx < 3) v = Wf[((size_t)o * FIN + i) * 9 + dy * 3 + dx];
        } else if (k == 12) {
            v = bf[o * FIN + i];
        }
        f16 hv = (f16)v;
        h[j] = *(unsigned short*)&hv;
    }
    uint4 pk;
    pk.x = h[0] | ((uint32)h[1] << 16);
    pk.y = h[2] | ((uint32)h[3] << 16);
    pk.z = h[4] | ((uint32)h[5] << 16);
    pk.w = h[6] | ((uint32)h[7] << 16);
    *(uint4*)&ws[(size_t)t * 8] = pk;
}

__global__ __launch_bounds__(512, 4) void conv_mfma(
    const float* __restrict__ x,  const float* __restrict__ Wc,
    const float* __restrict__ bc, const unsigned short* __restrict__ ws,
    float* __restrict__ out)
{
    __shared__ __align__(16) union {
        struct { uint32 xsl[2][XBUF]; float wcl[32][68]; } a;  // 16.4 KB
        float part[4][64][16];                                 // 16.4 KB
        float ot[32][132];                                     // 16.9 KB
    } sm;

    const int tid = threadIdx.x;          // 0..511, 8 waves
    const int l   = tid & 63, w = tid >> 6;
    const int wg  = w >> 2;               // channel group: 0 -> i 0..31, 1 -> 32..63
    const int wl  = w & 3;                // wave-in-group (round-10 "w" role)
    const int g   = l >> 5;
    const int m   = l & 31;               // pixel row idx on loads; o on output
    const int prow = m >> 2;
    const int sx   = wl * 4 + (m & 3);    // 0..15 tile col
    const bool odd = (sx & 1);
    const int  qd  = sx >> 1;
    const int ibase = wg * 32;

    // XCD-group swizzle: all 16 blocks sharing (rx,b) -> same fid%8 (same XCD)
    const int fid    = blockIdx.x;
    const int grp    = (fid >> 7) * 8 + (fid & 7);   // 0..63 = rx + 16*b
    const int member = (fid >> 3) & 15;              // cy + 8*oh
    const int rx = grp & 15, b = grp >> 4;
    const int cy = member & 7, oh = member >> 3;
    const int row0 = rx * TR;
    const int col0 = cy * TC;
    const int o_lane = oh * 32 + m;

    // ---- stage Wc [oo][i] (all 64 i; Wc input is already [o][i]) ----
#pragma unroll
    for (int k = 0; k < 4; ++k) {
        int idx = tid + k * 512;                      // 0..2047
        sm.a.wcl[idx >> 6][idx & 63] =
            Wc[(size_t)(oh * 32 + (idx >> 6)) * FIN + (idx & 63)];
    }

    // ---- staging map: 400 units (8 slots x 50), one aligned float4 each ----
    const float* xb = x + (size_t)b * FIN * HIWI;
    const bool stg = (tid < NUNIT);
    int slot = 0, goff = 0, widx = 0;
    if (stg) {
        slot = tid / 50;                       // 0..7: (group<<2)|c4
        int rem = tid % 50;
        int r = rem / 5, u = rem % 5;
        int gy = min(row0 + r, HI - 1);        // clamped lanes feed discarded outputs
        int gx = min(col0 + 4 * u, WI - 4);
        goff = gy * WI + gx;
        widx = slot * CHSTR + r * SDW + 2 * u; // even dword -> 8B-aligned write
    }
    const int chbase = (slot >> 2) * 32 + (slot & 3);   // channel at phase 0

    // prologue: stage phase 0 (channels {0..3, 32..35}) into buffer 0
    if (stg) {
        f32x4 v = *(const f32x4*)&xb[(size_t)chbase * HIWI + goff];
        f16x4 h; h[0] = (f16)v[0]; h[1] = (f16)v[1]; h[2] = (f16)v[2]; h[3] = (f16)v[3];
        *(uint2*)&sm.a.xsl[0][widx] = *(uint2*)&h;
    }

    // B-fragment prefetch for phase 0 (this group's channels)
    const uint4* Btab = (const uint4*)ws;
    uint4 Bc[4], Bn[4];
#pragma unroll
    for (int c4 = 0; c4 < 4; ++c4)
        Bc[c4] = Btab[(size_t)((ibase + c4) * 2 + oh) * 64 + l];

    f32x16 acc = {}, zero = {};

    for (int ph = 0; ph < NPH; ++ph) {         // plain loop: arrays stay in VGPRs
        const int cur = ph & 1;
        const bool more = (ph + 1 < NPH);

        f32x4 sv = {};
        if (more) {
            if (stg) sv = *(const f32x4*)
                &xb[(size_t)(chbase + (ph + 1) * 4) * HIWI + goff];
#pragma unroll
            for (int c4 = 0; c4 < 4; ++c4)
                Bn[c4] = Btab[(size_t)((ibase + (ph + 1) * 4 + c4) * 2 + oh) * 64 + l];
        }

        __syncthreads();   // buf[cur] writes from previous phase visible

        const f32x4 wcq = *(const f32x4*)&sm.a.wcl[m][ibase + ph * 4];
        const uint32* base = sm.a.xsl[cur];

#pragma unroll
        for (int c4 = 0; c4 < 4; ++c4) {
            const uint32* r1 = base + (wg * 4 + c4) * CHSTR + (prow + g) * SDW;
            const uint32* r2 = base + (wg * 4 + c4) * CHSTR + (prow + 2) * SDW;
            uint32 d0 = r1[qd], d1 = r1[qd + 1];
            uint32 e0 = r2[qd], e1 = r2[qd + 1];
            uint32 a0 = odd ? ((d0 >> 16) | (d1 << 16)) : d0;
            uint32 a1 = odd ? (d1 >> 16) : d1;
            uint32 b0 = odd ? ((e0 >> 16) | (e1 << 16)) : e0;
            uint32 b1 = odd ? (e1 >> 16) : e1;
            if (g) { b0 = 0x00003c00u; b1 = 0u; }          // bias slot: 1.0h
            uint4 auv = {a0, a1, b0, b1};
            f16x8 Af = *(f16x8*)&auv;
            f16x8 Bf = *(f16x8*)&Bc[c4];
            f32x16 S = __builtin_amdgcn_mfma_f32_32x32x16_f16(Af, Bf, zero, 0, 0, 0);
            const float wcv = wcq[c4];
#pragma unroll
            for (int r = 0; r < 16; ++r)
                acc[r] = fmaf(wcv, fmaxf(S[r], 0.0f), acc[r]);
        }

        if (more) {
            if (stg) {
                f16x4 h; h[0] = (f16)sv[0]; h[1] = (f16)sv[1];
                h[2] = (f16)sv[2]; h[3] = (f16)sv[3];
                *(uint2*)&sm.a.xsl[cur ^ 1][widx] = *(uint2*)&h;
            }
#pragma unroll
            for (int c4 = 0; c4 < 4; ++c4) Bc[c4] = Bn[c4];
        }
    }

    // ---- combine the two channel groups via LDS (deterministic fp32) ----
    __syncthreads();                       // all xsl reads done (part aliases xsl)
    if (wg == 1) {
#pragma unroll
        for (int r = 0; r < 16; ++r) sm.part[wl][l][r] = acc[r];
    }
    __syncthreads();
    if (wg == 0) {
#pragma unroll
        for (int r = 0; r < 16; ++r) acc[r] += sm.part[wl][l][r];
    }
    __syncthreads();                       // part reads done (ot aliases part)

    // ---- transpose: ot[o][px] (group-0 waves only) ----
    if (wg == 0) {
        const float bcv = bc[o_lane];
#pragma unroll
        for (int r = 0; r < 16; ++r) {
            int p  = (r & 3) + 8 * (r >> 2) + 4 * g;             // wave-local pixel
            int px = (p >> 2) * TC + wl * 4 + (p & 3);
            sm.ot[m][px] = acc[r] + bcv;
        }
    }
    __syncthreads();

    // ---- stores: one 16-col row chunk (64B) per thread (first 256 threads) ----
    if (tid < 256) {
        const int oo  = tid >> 3;          // 0..31
        const int seg = tid & 7;           // tile row
        const int o   = oh * 32 + oo;
        const int ho  = row0 + seg;
        if (ho < HO) {
            const float* src = &sm.ot[oo][seg * TC];
            size_t base = ((size_t)(b * FOUT + o) * HO + ho) * WO + col0;
            const int nst = (col0 + TC <= WO) ? TC : (WO - col0);
            for (int c = 0; c < nst; ++c) out[base + c] = src[c];
        }
    }
}

extern "C" void kernel_launch(void* const* d_in, const int* in_sizes, int n_in,
                              void* d_out, int out_size, void* d_ws, size_t ws_size,
                              hipStream_t stream) {
    const float* x  = (const float*)d_in[0];
    const float* Wf = (const float*)d_in[1];
    const float* bf = (const float*)d_in[2];
    const float* Wc = (const float*)d_in[3];
    const float* bc = (const float*)d_in[4];
    float* out = (float*)d_out;
    unsigned short* ws = (unsigned short*)d_ws;

    hipLaunchKernelGGL(prepass, dim3(32), dim3(256), 0, stream, Wf, bf, ws);

    // 1024 blocks x 512 threads: 16 rx x (8 cy x 2 oh) x 4 b, XCD-group swizzled
    hipLaunchKernelGGL(conv_mfma, dim3(1024), dim3(512), 0, stream,
                       x, Wc, bc, ws, out);
}

// Round 16
// 44.540 us; speedup vs baseline: 6.4907x; 1.0494x over previous
//
#include <hip/hip_runtime.h>

typedef _Float16 f16;
typedef __fp16 h2 __attribute__((ext_vector_type(2)));
typedef f16 f16x4 __attribute__((ext_vector_type(4)));
typedef f16 f16x8 __attribute__((ext_vector_type(8)));
typedef float f32x4 __attribute__((ext_vector_type(4)));
typedef float f32x16 __attribute__((ext_vector_type(16)));
typedef unsigned int uint32;

#define FIN  64
#define FOUT 64
#define HI   128
#define WI   128
#define HO   126
#define WO   126
#define HIWI (HI*WI)
#define NPH  8       // phases; each stages 8 channels (4 per wave-group)
#define TR   8       // tile rows
#define TC   16      // tile cols
#define SR   10      // staged rows (TR+2)
#define SDW  12      // dwords per staged row (10 used, 2 pad)
#define CHSTR (SR*SDW)     // 120 dwords per channel slot
#define NSLOT 8            // channel slots per phase (2 groups x 4)
#define ONES_OFF (NSLOT*CHSTR)   // 960: shared 1.0h row (bias slot)
#define XBUF (ONES_OFF+SDW)      // 972 dwords per buffer

// ws: B-fragment table f16 [i][ob][lane][8] = 128 KiB; Wc f16-pair table
// u32 [ipair][o] (64 o) = 8 KiB at u32 offset 32768.
// k-labeling (validated rounds 6/8/9/10): k = g*4+(j&3)+8*(j>>2), g=lane>>5;
// taps k=4*dy+dx (dx<3 real, dx=3 zero-weight), k12 = bias (pixel side = 1.0h).
// LESSONS: (r11) no address-of MFMA results; (r12) no register arrays by
// reference; (r14) watch the VGPR budget — spills show as GB-scale FETCH/WRITE.

__global__ __launch_bounds__(256) void prepass(
    const float* __restrict__ Wf, const float* __restrict__ bf,
    const float* __restrict__ Wc, unsigned short* __restrict__ ws)
{
    int t = blockIdx.x * 256 + threadIdx.x;   // 0..10239
    if (t < 8192) {
        int i  = t >> 7;
        int ob = (t >> 6) & 1;
        int l  = t & 63;
        int g  = l >> 5, n = l & 31;
        int o  = ob * 32 + n;
        unsigned short h[8];
#pragma unroll
        for (int j = 0; j < 8; ++j) {
            int k = g * 4 + (j & 3) + 8 * (j >> 2);
            float v = 0.0f;
            if (k < 12) {
                int dy = k >> 2, dx = k & 3;
                if (dx < 3) v = Wf[((size_t)o * FIN + i) * 9 + dy * 3 + dx];
            } else if (k == 12) {
                v = bf[o * FIN + i];
            }
            f16 hv = (f16)v;
            h[j] = *(unsigned short*)&hv;
        }
        uint4 pk;
        pk.x = h[0] | ((uint32)h[1] << 16);
        pk.y = h[2] | ((uint32)h[3] << 16);
        pk.z = h[4] | ((uint32)h[5] << 16);
        pk.w = h[6] | ((uint32)h[7] << 16);
        *(uint4*)&ws[(size_t)t * 8] = pk;
    } else if (t < 8192 + 2048) {
        // Wc pair table: u32[ip][o] = f16(Wc[o][2ip]) | f16(Wc[o][2ip+1])<<16
        int t2 = t - 8192;
        int ip = t2 >> 6, o = t2 & 63;
        f16 lo = (f16)Wc[(size_t)o * FIN + 2 * ip];
        f16 hi = (f16)Wc[(size_t)o * FIN + 2 * ip + 1];
        uint32 v = (uint32)*(unsigned short*)&lo |
                   ((uint32)*(unsigned short*)&hi << 16);
        ((uint32*)ws)[32768 + t2] = v;
    }
}

__global__ __launch_bounds__(512, 4) void conv_mfma(
    const float* __restrict__ x,  const float* __restrict__ bc,
    const unsigned short* __restrict__ ws, float* __restrict__ out)
{
    __shared__ __align__(16) union {
        struct { uint32 xsl[2][XBUF]; uint32 wcp[32][34]; } a;  // 12.1 KB
        float part[4][64][16];                                  // 16.4 KB
        float ot[32][132];                                      // 16.9 KB
    } sm;

    const int tid = threadIdx.x;          // 0..511, 8 waves
    const int l   = tid & 63, w = tid >> 6;
    const int wg  = w >> 2;               // channel group: 0 -> i 0..31, 1 -> 32..63
    const int wl  = w & 3;                // wave-in-group
    const int g   = l >> 5;
    const int m   = l & 31;               // pixel row idx on loads; o on output
    const int prow = m >> 2;
    // wave-uniform column parity (r12/r13): even wl-pairs own even cols
    const int qd   = (wl & 1) * 4 + (m & 3);   // first dword of the window
    const int shl  = (wl >> 1) * 16;           // alignbit shift: 0 or 16 (uniform)
    const int ibase = wg * 32;

    // XCD-group swizzle: all 16 blocks sharing (rx,b) -> same fid%8 (same XCD)
    const int fid    = blockIdx.x;
    const int grp    = (fid >> 7) * 8 + (fid & 7);   // 0..63 = rx + 16*b
    const int member = (fid >> 3) & 15;              // cy + 8*oh
    const int rx = grp & 15, b = grp >> 4;
    const int cy = member & 7, oh = member >> 3;
    const int row0 = rx * TR;
    const int col0 = cy * TC;
    const int o_lane = oh * 32 + m;

    // ---- stage Wc pair table [oo][ip] (1024 u32, once) ----
    {
        const uint32* wsrc = ((const uint32*)ws) + 32768;
#pragma unroll
        for (int k = 0; k < 2; ++k) {
            int idx = tid + k * 512;                  // 0..1023
            int oo = idx >> 5, ip = idx & 31;
            sm.a.wcp[oo][ip] = wsrc[(size_t)ip * 64 + oh * 32 + oo];
        }
    }
    // ones rows (bias slot source), both buffers
    if (tid < 2 * SDW) sm.a.xsl[tid / SDW][ONES_OFF + tid % SDW] = 0x3c003c00u;

    // ---- balanced staging: wave w stages slot w (50 lanes each) ----
    const float* xb = x + (size_t)b * FIN * HIWI;
    const bool stg = (l < 50);
    int goff = 0, widx = 0;
    if (stg) {
        int r = l / 5, u = l % 5;
        int gy = min(row0 + r, HI - 1);        // clamped lanes feed discarded outputs
        int gx = min(col0 + 4 * u, WI - 4);
        goff = gy * WI + gx;
        widx = w * CHSTR + r * SDW + 2 * u;    // even dword -> 8B-aligned write
    }
    const int chbase = wg * 32 + wl;           // slot w's channel at phase 0

    // prologue: stage phase 0 (channels {0..3, 32..35}) into buffer 0
    if (stg) {
        f32x4 v = *(const f32x4*)&xb[(size_t)chbase * HIWI + goff];
        f16x4 h; h[0] = (f16)v[0]; h[1] = (f16)v[1]; h[2] = (f16)v[2]; h[3] = (f16)v[3];
        *(uint2*)&sm.a.xsl[0][widx] = *(uint2*)&h;
    }

    // B-fragment prefetch for phase 0 (this group's channels)
    const uint4* Btab = (const uint4*)ws;
    uint4 Bc[4], Bn[4];
#pragma unroll
    for (int c4 = 0; c4 < 4; ++c4)
        Bc[c4] = Btab[(size_t)((ibase + c4) * 2 + oh) * 64 + l];

    f32x16 acc = {}, zero = {};
    const h2 zh = {(__fp16)0.0f, (__fp16)0.0f};

    // hoisted read offsets (per-thread constants)
    const int r1off = (prow + g) * SDW + qd;
    const int r2off = g ? (ONES_OFF + qd) : ((prow + 2) * SDW + qd);
    const int r2str = g ? 0 : CHSTR;

    for (int ph = 0; ph < NPH; ++ph) {         // plain loop: arrays stay in VGPRs
        const int cur = ph & 1;
        const bool more = (ph + 1 < NPH);

        f32x4 sv = {};
        if (more) {
            if (stg) sv = *(const f32x4*)
                &xb[(size_t)(chbase + (ph + 1) * 4) * HIWI + goff];
#pragma unroll
            for (int c4 = 0; c4 < 4; ++c4)
                Bn[c4] = Btab[(size_t)((ibase + (ph + 1) * 4 + c4) * 2 + oh) * 64 + l];
        }

        __syncthreads();   // buf[cur] writes from previous phase visible

        const uint32 wcu0 = sm.a.wcp[m][wg * 16 + ph * 2];
        const uint32 wcu1 = sm.a.wcp[m][wg * 16 + ph * 2 + 1];
        const uint32* base = sm.a.xsl[cur];

#pragma unroll
        for (int c2 = 0; c2 < 2; ++c2) {       // channel pairs
            const int ch0 = 2 * c2, ch1 = 2 * c2 + 1;
            const uint32* r1a = base + (wg * 4 + ch0) * CHSTR + r1off;
            const uint32* r2a = base + (wg * 4 + ch0) * r2str + r2off;
            uint32 d0 = r1a[0], d1 = r1a[1], d2 = r1a[2];
            uint32 e0 = r2a[0], e1 = r2a[1], e2 = r2a[2];
            uint4 auv0 = {__builtin_amdgcn_alignbit(d1, d0, shl),
                          __builtin_amdgcn_alignbit(d2, d1, shl),
                          __builtin_amdgcn_alignbit(e1, e0, shl),
                          __builtin_amdgcn_alignbit(e2, e1, shl)};
            f16x8 Af0 = *(f16x8*)&auv0;
            f32x16 S0 = __builtin_amdgcn_mfma_f32_32x32x16_f16(
                            Af0, *(f16x8*)&Bc[ch0], zero, 0, 0, 0);

            const uint32* r1b = base + (wg * 4 + ch1) * CHSTR + r1off;
            const uint32* r2b = base + (wg * 4 + ch1) * r2str + r2off;
            uint32 f0 = r1b[0], f1 = r1b[1], f2 = r1b[2];
            uint32 k0 = r2b[0], k1 = r2b[1], k2 = r2b[2];
            uint4 auv1 = {__builtin_amdgcn_alignbit(f1, f0, shl),
                          __builtin_amdgcn_alignbit(f2, f1, shl),
                          __builtin_amdgcn_alignbit(k1, k0, shl),
                          __builtin_amdgcn_alignbit(k2, k1, shl)};
            f16x8 Af1 = *(f16x8*)&auv1;
            f32x16 S1 = __builtin_amdgcn_mfma_f32_32x32x16_f16(
                            Af1, *(f16x8*)&Bc[ch1], zero, 0, 0, 0);

            const uint32 wcu = c2 ? wcu1 : wcu0;
            h2 wch;
            {
                uint32 t = wcu;
                wch = *(h2*)&t;            // local scalar, SSA-safe
            }
#pragma unroll
            for (int r = 0; r < 16; ++r) {
                h2 p = __builtin_amdgcn_cvt_pkrtz(S0[r], S1[r]);   // relu'd pair
                p = __builtin_elementwise_max(p, zh);              // v_pk_max_f16
                acc[r] = __builtin_amdgcn_fdot2(p, wch, acc[r], false);
            }
        }

        if (more) {
            if (stg) {
                f16x4 h; h[0] = (f16)sv[0]; h[1] = (f16)sv[1];
                h[2] = (f16)sv[2]; h[3] = (f16)sv[3];
                *(uint2*)&sm.a.xsl[cur ^ 1][widx] = *(uint2*)&h;
            }
#pragma unroll
            for (int c4 = 0; c4 < 4; ++c4) Bc[c4] = Bn[c4];
        }
    }

    // ---- combine the two channel groups via LDS (deterministic fp32) ----
    __syncthreads();                       // all xsl reads done (part aliases xsl)
    if (wg == 1) {
#pragma unroll
        for (int r = 0; r < 16; ++r) sm.part[wl][l][r] = acc[r];
    }
    __syncthreads();
    if (wg == 0) {
#pragma unroll
        for (int r = 0; r < 16; ++r) acc[r] += sm.part[wl][l][r];
    }
    __syncthreads();                       // part reads done (ot aliases part)

    // ---- transpose: ot[o][px] (group-0 waves only) ----
    if (wg == 0) {
        const float bcv = bc[o_lane];
#pragma unroll
        for (int r = 0; r < 16; ++r) {
            int p  = (r & 3) + 8 * (r >> 2) + 4 * g;             // wave-local pixel
            int px = (p >> 2) * TC + (wl & 1) * 8 + 2 * (p & 3) + (wl >> 1);
            sm.ot[m][px] = acc[r] + bcv;
        }
    }
    __syncthreads();

    // ---- stores: one 16-col row chunk (64B) per thread (first 256 threads) ----
    if (tid < 256) {
        const int oo  = tid >> 3;          // 0..31
        const int seg = tid & 7;           // tile row
        const int o   = oh * 32 + oo;
        const int ho  = row0 + seg;
        if (ho < HO) {
            const float* src = &sm.ot[oo][seg * TC];
            size_t base = ((size_t)(b * FOUT + o) * HO + ho) * WO + col0;
            if (col0 + TC <= WO) {
#pragma unroll
                for (int c = 0; c < TC; ++c) out[base + c] = src[c];
            } else {
#pragma unroll
                for (int c = 0; c < 14; ++c) out[base + c] = src[c];
            }
        }
    }
}

extern "C" void kernel_launch(void* const* d_in, const int* in_sizes, int n_in,
                              void* d_out, int out_size, void* d_ws, size_t ws_size,
                              hipStream_t stream) {
    const float* x  = (const float*)d_in[0];
    const float* Wf = (const float*)d_in[1];
    const float* bf = (const float*)d_in[2];
    const float* Wc = (const float*)d_in[3];
    const float* bc = (const float*)d_in[4];
    float* out = (float*)d_out;
    unsigned short* ws = (unsigned short*)d_ws;

    hipLaunchKernelGGL(prepass, dim3(40), dim3(256), 0, stream, Wf, bf, Wc, ws);

    // 1024 blocks x 512 threads: 16 rx x (8 cy x 2 oh) x 4 b, XCD-group swizzled
    hipLaunchKernelGGL(conv_mfma, dim3(1024), dim3(512), 0, stream,
                       x, bc, ws, out);
}